// Round 15
// baseline (580.900 us; speedup 1.0000x reference)
//
#include <hip/hip_runtime.h>
#include <stdint.h>

typedef unsigned short u16;
typedef short bf16x8 __attribute__((ext_vector_type(8)));
typedef float f32x4 __attribute__((ext_vector_type(4)));

constexpr int B_ = 2, V_ = 50000, E_ = 400000;
constexpr int FIN_ = 128, COND_ = 32, HID_ = 256, OUT_ = 128, ENC_ = 64;
constexpr int M_ = B_ * V_;          // 100000
constexpr int MP_ = M_ + 256;        // padded rows
constexpr int K0_ = FIN_ + COND_;    // 160
constexpr float EPS_ = 1e-5f;

#define DEV static __device__ __forceinline__

DEV float b2f(u16 u) { union { float f; uint32_t i; } x; x.i = ((uint32_t)u) << 16; return x.f; }
DEV u16 f2b(float f) {
  union { float f; uint32_t i; } x; x.f = f;
  uint32_t r = x.i + 0x7fffu + ((x.i >> 16) & 1u);
  return (u16)(r >> 16);
}
DEV uint32_t pk2(float a, float b) { return (uint32_t)f2b(a) | ((uint32_t)f2b(b) << 16); }

// ---------------- graph preprocessing ----------------
__global__ void k_count(const int* __restrict__ dst, int* __restrict__ cnt) {
  int e = blockIdx.x * blockDim.x + threadIdx.x;
  if (e < E_) atomicAdd(&cnt[dst[e]], 1);
}

__global__ void k_dinv(const int* __restrict__ cnt, float* __restrict__ dinv) {
  int v = blockIdx.x * blockDim.x + threadIdx.x;
  if (v < V_) dinv[v] = rsqrtf(1.0f + (float)cnt[v]);
}

__global__ __launch_bounds__(1024) void k_scan1(const int* __restrict__ cnt,
                                                int* __restrict__ tmp, int* __restrict__ bsum) {
  __shared__ int s[1024];
  int tid = threadIdx.x;
  int i = blockIdx.x * 1024 + tid;
  int v = (i < V_) ? cnt[i] : 0;
  s[tid] = v;
  __syncthreads();
  for (int off = 1; off < 1024; off <<= 1) {
    int t = (tid >= off) ? s[tid - off] : 0;
    __syncthreads();
    s[tid] += t;
    __syncthreads();
  }
  if (i < V_) tmp[i] = s[tid];
  if (tid == 1023) bsum[blockIdx.x] = s[1023];
}

__global__ void k_scan2(int* __restrict__ bsum, int n) {
  if (threadIdx.x == 0) {
    int a = 0;
    for (int i = 0; i < n; ++i) { a += bsum[i]; bsum[i] = a; }
  }
}

__global__ void k_scan3(const int* __restrict__ cnt, const int* __restrict__ tmp,
                        const int* __restrict__ bsum, int* __restrict__ row_ptr,
                        int* __restrict__ cursor) {
  int i = blockIdx.x * blockDim.x + threadIdx.x;
  if (i >= V_) return;
  int blk = i >> 10;
  int offs = blk ? bsum[blk - 1] : 0;
  int incl = tmp[i] + offs;
  row_ptr[i + 1] = incl;
  cursor[i] = incl - cnt[i];
  if (i == 0) row_ptr[0] = 0;
}

__global__ void k_fill(const int* __restrict__ src, const int* __restrict__ dst,
                       const float* __restrict__ dinv,
                       int* __restrict__ cursor, int2* __restrict__ csr) {
  int e = blockIdx.x * blockDim.x + threadIdx.x;
  if (e < E_) {
    int s = src[e], d = dst[e];
    int p = atomicAdd(&cursor[d], 1);
    float cf = dinv[s] * dinv[d];
    csr[p] = make_int2(s, __float_as_int(cf));
  }
}

// rowsum[v] = dv^2 + sum of edge coefs (for GN affine commute)
__global__ void k_rowsum(const float* __restrict__ dinv, const int* __restrict__ row_ptr,
                         const int2* __restrict__ csr, float* __restrict__ rowsum) {
  int v = blockIdx.x * blockDim.x + threadIdx.x;
  if (v >= V_) return;
  float dv = dinv[v];
  float s = dv * dv;
  int e = row_ptr[v + 1];
  for (int j = row_ptr[v]; j < e; ++j) s += __int_as_float(csr[j].y);
  rowsum[v] = s;
}

// ---------------- small dense helpers ----------------
__global__ void k_film(const float* __restrict__ t, const float* __restrict__ fw,
                       const float* __restrict__ fb, float* __restrict__ gb) {
  int b = blockIdx.x; int j = threadIdx.x;   // blockDim = 512
  float acc = fb[j];
  for (int k = 0; k < ENC_; ++k) acc += t[b * ENC_ + k] * fw[k * 512 + j];
  gb[b * 512 + j] = acc;
}

__global__ void k_wconv(const float* __restrict__ W, u16* __restrict__ WT, int K, int N) {
  int idx = blockIdx.x * blockDim.x + threadIdx.x;
  if (idx < K * N) {
    int k = idx / N, n = idx % N;
    WT[n * K + k] = f2b(W[idx]);
  }
}

__global__ void k_wconv_g(const float* __restrict__ W, const float* __restrict__ gng,
                          u16* __restrict__ WT, int K, int N) {
  int idx = blockIdx.x * blockDim.x + threadIdx.x;
  if (idx < K * N) {
    int k = idx / N, n = idx % N;
    WT[n * K + k] = f2b(W[idx] * gng[k]);
  }
}

__global__ void k_gnreduce(const float4* __restrict__ part, int nblk,
                           float* __restrict__ stats) {
  int tid = threadIdx.x;  // 256
  float s0 = 0.f, ss0 = 0.f, s1 = 0.f, ss1 = 0.f;
  for (int i = tid; i < nblk; i += 256) {
    float4 p = part[i];
    s0 += p.x; ss0 += p.y; s1 += p.z; ss1 += p.w;
  }
  __shared__ float red[4][4];
#pragma unroll
  for (int o = 32; o > 0; o >>= 1) {
    s0  += __shfl_down(s0, o, 64);
    ss0 += __shfl_down(ss0, o, 64);
    s1  += __shfl_down(s1, o, 64);
    ss1 += __shfl_down(ss1, o, 64);
  }
  int w = tid >> 6, ln = tid & 63;
  if (ln == 0) { red[w][0] = s0; red[w][1] = ss0; red[w][2] = s1; red[w][3] = ss1; }
  __syncthreads();
  if (tid == 0) {
    float S0 = red[0][0] + red[1][0] + red[2][0] + red[3][0];
    float SS0 = red[0][1] + red[1][1] + red[2][1] + red[3][1];
    float S1 = red[0][2] + red[1][2] + red[2][2] + red[3][2];
    float SS1 = red[0][3] + red[1][3] + red[2][3] + red[3][3];
    float n = (float)V_ * (float)HID_;
    float mu0 = S0 / n, var0 = SS0 / n - mu0 * mu0;
    float mu1 = S1 / n, var1 = SS1 / n - mu1 * mu1;
    stats[0] = mu0; stats[1] = rsqrtf(var0 + EPS_);
    stats[2] = mu1; stats[3] = rsqrtf(var1 + EPS_);
  }
}

__global__ void k_gnfold(const float* __restrict__ gng, const float* __restrict__ gnb,
                         const float* __restrict__ W, const float* __restrict__ stats,
                         float* __restrict__ kc) {
  int n = blockIdx.x, c = threadIdx.x;
  float wv = W[c * HID_ + n];
  float gw = gng[c] * wv, bw = gnb[c] * wv;
  __shared__ float sg[4], sb[4];
#pragma unroll
  for (int o = 32; o > 0; o >>= 1) {
    gw += __shfl_down(gw, o, 64);
    bw += __shfl_down(bw, o, 64);
  }
  int w = c >> 6, ln = c & 63;
  if (ln == 0) { sg[w] = gw; sb[w] = bw; }
  __syncthreads();
  if (c == 0) {
    float G = sg[0] + sg[1] + sg[2] + sg[3];
    float Bw = sb[0] + sb[1] + sb[2] + sb[3];
    for (int b = 0; b < B_; ++b)
      kc[b * HID_ + n] = Bw - stats[b * 2] * stats[b * 2 + 1] * G;
  }
}

__global__ void k_prep0(const float* __restrict__ x, const float* __restrict__ cond,
                        u16* __restrict__ A0) {
  int idx = blockIdx.x * blockDim.x + threadIdx.x;
  if (idx >= M_ * K0_ / 4) return;
  int e = idx * 4;
  int r = e / K0_, c = e % K0_;
  float4 v;
  if (c < FIN_) v = *(const float4*)&x[(size_t)r * FIN_ + c];
  else { int vv = r % V_; v = *(const float4*)&cond[(size_t)vv * COND_ + (c - FIN_)]; }
  uint2 o;
  o.x = pk2(v.x, v.y);
  o.y = pk2(v.z, v.w);
  *(uint2*)&A0[e] = o;
}

// ---------------- GCN gather: PURE aggregation (R10-proven) ----------------
template<int KW>
__global__ __launch_bounds__(256) void k_gather(
    const u16* __restrict__ hw, const float* __restrict__ dinv,
    const int* __restrict__ row_ptr, const int2* __restrict__ csr,
    u16* __restrict__ out)
{
  __shared__ f32x4 redA[3][2][32];
  __shared__ f32x4 redB[3][2][32];
  const int v   = blockIdx.x;
  const int tid = threadIdx.x;
  const int nb  = tid >> 6;
  const int b   = (tid >> 5) & 1;
  const int l   = tid & 31;
  const int c0  = l * 8;
  const bool act = l < (KW / 8);

  const float dv = dinv[v];
  const int beg = row_ptr[v], end = row_ptr[v + 1];

  float acc[8];
#pragma unroll
  for (int k = 0; k < 8; ++k) acc[k] = 0.f;

  if (act) {
    int j = beg + nb;
    for (; j + 4 < end; j += 8) {
      int2 e0 = csr[j];
      int2 e1 = csr[j + 4];
      float cf0 = __int_as_float(e0.y);
      float cf1 = __int_as_float(e1.y);
      uint4 u0 = *(const uint4*)&hw[((size_t)b * V_ + e0.x) * KW + c0];
      uint4 u1 = *(const uint4*)&hw[((size_t)b * V_ + e1.x) * KW + c0];
      u16 a0[8]; *(uint4*)a0 = u0;
      u16 a1[8]; *(uint4*)a1 = u1;
#pragma unroll
      for (int k = 0; k < 8; ++k) acc[k] += b2f(a0[k]) * cf0;
#pragma unroll
      for (int k = 0; k < 8; ++k) acc[k] += b2f(a1[k]) * cf1;
    }
    if (j < end) {
      int2 e0 = csr[j];
      float cf0 = __int_as_float(e0.y);
      uint4 u0 = *(const uint4*)&hw[((size_t)b * V_ + e0.x) * KW + c0];
      u16 a0[8]; *(uint4*)a0 = u0;
#pragma unroll
      for (int k = 0; k < 8; ++k) acc[k] += b2f(a0[k]) * cf0;
    }
  }

  if (nb > 0) {
    redA[nb - 1][b][l] = f32x4{acc[0], acc[1], acc[2], acc[3]};
    redB[nb - 1][b][l] = f32x4{acc[4], acc[5], acc[6], acc[7]};
  }
  __syncthreads();
  if (nb == 0 && act) {
#pragma unroll
    for (int g = 0; g < 3; ++g) {
      f32x4 ra = redA[g][b][l], rb = redB[g][b][l];
      acc[0] += ra[0]; acc[1] += ra[1]; acc[2] += ra[2]; acc[3] += ra[3];
      acc[4] += rb[0]; acc[5] += rb[1]; acc[6] += rb[2]; acc[7] += rb[3];
    }
    float sl = dv * dv;
    uint4 u = *(const uint4*)&hw[((size_t)b * V_ + v) * KW + c0];
    u16 us[8]; *(uint4*)us = u;
#pragma unroll
    for (int k = 0; k < 8; ++k) acc[k] += b2f(us[k]) * sl;
    uint4 o;
    o.x = pk2(acc[0], acc[1]);
    o.y = pk2(acc[2], acc[3]);
    o.z = pk2(acc[4], acc[5]);
    o.w = pk2(acc[6], acc[7]);
    *(uint4*)&out[((size_t)b * V_ + v) * KW + c0] = o;
  }
}

// ---------------- fused dual-GEMM, BARRIER-FREE phases ----------------
// N is small (<=256) and W1/W2 are L2/L3-hot: load BOTH operand fragments
// per-lane directly from global (exact MFMA operand layout, no LDS staging,
// no per-K-step barriers). Only the inter-GEMM intermediate T1 uses LDS
// (32 KB, granule-XOR), with ONE barrier between epilogue-1 and phase 2.
// P1E: 0=bias+relu, 1=GN-fold (rs*v + rowsum*kc + bias, relu), 2=bias+FiLM+relu
// P2E: 0=bias+relu->bf16, 1=bias+relu->bf16 + GN stats partials, 2=bias+xres->f32
template<int P1E, int P2E, int K1, int N2>
__global__ __launch_bounds__(256) void k_pair(
    const u16* __restrict__ A, const u16* __restrict__ W1T, const u16* __restrict__ W2T,
    const float* __restrict__ b1, const float* __restrict__ b2,
    const float* __restrict__ stats, const float* __restrict__ kc,
    const float* __restrict__ rowsum, const float* __restrict__ gb,
    const float* __restrict__ xres, float4* __restrict__ part,
    void* __restrict__ Out)
{
  constexpr int BM = 64, N1 = 256;
  constexpr int FN2 = N2 / 64;
  __shared__ alignas(16) u16 T1[BM * N1];      // 32 KB
  __shared__ float sred[4][4];
  const int tile_m = blockIdx.x * BM;
  const int tid = threadIdx.x;
  const int wave = tid >> 6, lane = tid & 63;
  const int lr = lane & 15, lkg = lane >> 4;

  // ---------------- phase 1: direct-from-global GEMM (no LDS, no barriers) ----
  f32x4 acc[4][4];
#pragma unroll
  for (int i = 0; i < 4; ++i)
#pragma unroll
    for (int j = 0; j < 4; ++j) acc[i][j] = {0.f, 0.f, 0.f, 0.f};

  for (int kb = 0; kb < K1; kb += 32) {
    bf16x8 af[4], bf[4];
#pragma unroll
    for (int fm = 0; fm < 4; ++fm)
      af[fm] = *(const bf16x8*)&A[(size_t)(tile_m + fm * 16 + lr) * K1 + kb + lkg * 8];
#pragma unroll
    for (int fn = 0; fn < 4; ++fn)
      bf[fn] = *(const bf16x8*)&W1T[(size_t)(wave * 64 + fn * 16 + lr) * K1 + kb + lkg * 8];
#pragma unroll
    for (int fm = 0; fm < 4; ++fm)
#pragma unroll
      for (int fn = 0; fn < 4; ++fn)
        acc[fm][fn] = __builtin_amdgcn_mfma_f32_16x16x32_bf16(bf[fn], af[fm], acc[fm][fn], 0, 0, 0);
  }

  // epilogue 1 -> T1 (granule-XOR swizzle; R10-proven layout)
#pragma unroll
  for (int fm = 0; fm < 4; ++fm) {
    const int row = fm * 16 + lr;
    const int gr = tile_m + row;
    const int bb = (gr >= V_) ? 1 : 0;
    float rsc = 1.f, rsum = 0.f;
    if (P1E == 1) {
      rsc = stats[bb * 2 + 1];
      int node = (gr < M_) ? (gr - bb * V_) : 0;
      rsum = rowsum[node];
    }
#pragma unroll
    for (int fn = 0; fn < 4; ++fn) {
      const int colb = wave * 64 + fn * 16 + lkg * 4;
      float v0 = acc[fm][fn][0], v1 = acc[fm][fn][1];
      float v2 = acc[fm][fn][2], v3 = acc[fm][fn][3];
      float4 bs = *(const float4*)&b1[colb];
      if (P1E == 0) {
        v0 = fmaxf(v0 + bs.x, 0.f); v1 = fmaxf(v1 + bs.y, 0.f);
        v2 = fmaxf(v2 + bs.z, 0.f); v3 = fmaxf(v3 + bs.w, 0.f);
      }
      if (P1E == 1) {
        float4 kcv = *(const float4*)&kc[bb * 256 + colb];
        v0 = fmaxf(v0 * rsc + rsum * kcv.x + bs.x, 0.f);
        v1 = fmaxf(v1 * rsc + rsum * kcv.y + bs.y, 0.f);
        v2 = fmaxf(v2 * rsc + rsum * kcv.z + bs.z, 0.f);
        v3 = fmaxf(v3 * rsc + rsum * kcv.w + bs.w, 0.f);
      }
      if (P1E == 2) {
        float4 g = *(const float4*)&gb[bb * 512 + colb];
        float4 be = *(const float4*)&gb[bb * 512 + 256 + colb];
        v0 = fmaxf((v0 + bs.x) * g.x + be.x, 0.f);
        v1 = fmaxf((v1 + bs.y) * g.y + be.y, 0.f);
        v2 = fmaxf((v2 + bs.z) * g.z + be.z, 0.f);
        v3 = fmaxf((v3 + bs.w) * g.w + be.w, 0.f);
      }
      int pg = (colb >> 2) ^ ((row & 7) << 1);
      uint2 o; o.x = pk2(v0, v1); o.y = pk2(v2, v3);
      *(uint2*)&T1[row * 256 + pg * 4] = o;
    }
  }
  __syncthreads();   // the ONLY inter-phase barrier

  // ---------------- phase 2: T1 (LDS) @ W2 (global) ----------------
  f32x4 acc2[4][FN2];
#pragma unroll
  for (int i = 0; i < 4; ++i)
#pragma unroll
    for (int j = 0; j < FN2; ++j) acc2[i][j] = {0.f, 0.f, 0.f, 0.f};

  for (int kb2 = 0; kb2 < 256; kb2 += 32) {
    bf16x8 af2[4], bf2[FN2];
#pragma unroll
    for (int fm = 0; fm < 4; ++fm) {
      int row = fm * 16 + lr;
      int pg = ((kb2 >> 2) + lkg * 2) ^ ((row & 7) << 1);
      af2[fm] = *(const bf16x8*)&T1[row * 256 + pg * 4];
    }
#pragma unroll
    for (int fn = 0; fn < FN2; ++fn)
      bf2[fn] = *(const bf16x8*)&W2T[(size_t)(wave * (N2 / 4) + fn * 16 + lr) * 256 + kb2 + lkg * 8];
#pragma unroll
    for (int fm = 0; fm < 4; ++fm)
#pragma unroll
      for (int fn = 0; fn < FN2; ++fn)
        acc2[fm][fn] = __builtin_amdgcn_mfma_f32_16x16x32_bf16(bf2[fn], af2[fm], acc2[fm][fn], 0, 0, 0);
  }

  // epilogue 2 -> global
  float s0 = 0.f, ss0 = 0.f, s1 = 0.f, ss1 = 0.f;
#pragma unroll
  for (int fm = 0; fm < 4; ++fm) {
    const int row = tile_m + fm * 16 + lr;
    if (row >= M_) continue;
#pragma unroll
    for (int fn = 0; fn < FN2; ++fn) {
      const int colb = wave * (N2 / 4) + fn * 16 + lkg * 4;
      float v0 = acc2[fm][fn][0], v1 = acc2[fm][fn][1];
      float v2 = acc2[fm][fn][2], v3 = acc2[fm][fn][3];
      float4 bs = *(const float4*)&b2[colb];
      if (P2E == 0 || P2E == 1) {
        v0 = fmaxf(v0 + bs.x, 0.f); v1 = fmaxf(v1 + bs.y, 0.f);
        v2 = fmaxf(v2 + bs.z, 0.f); v3 = fmaxf(v3 + bs.w, 0.f);
        if (P2E == 1) {
          if (row >= V_) { s1 += v0 + v1 + v2 + v3; ss1 += v0*v0 + v1*v1 + v2*v2 + v3*v3; }
          else           { s0 += v0 + v1 + v2 + v3; ss0 += v0*v0 + v1*v1 + v2*v2 + v3*v3; }
        }
        uint2 o; o.x = pk2(v0, v1); o.y = pk2(v2, v3);
        *(uint2*)&((u16*)Out)[(size_t)row * N2 + colb] = o;
      } else {
        float4 xr = *(const float4*)&xres[(size_t)row * N2 + colb];
        float4 o;
        o.x = v0 + bs.x + xr.x; o.y = v1 + bs.y + xr.y;
        o.z = v2 + bs.z + xr.z; o.w = v3 + bs.w + xr.w;
        *(float4*)&((float*)Out)[(size_t)row * N2 + colb] = o;
      }
    }
  }
  if (P2E == 1) {
#pragma unroll
    for (int o = 32; o > 0; o >>= 1) {
      s0  += __shfl_down(s0, o, 64);
      ss0 += __shfl_down(ss0, o, 64);
      s1  += __shfl_down(s1, o, 64);
      ss1 += __shfl_down(ss1, o, 64);
    }
    if (lane == 0) { sred[wave][0] = s0; sred[wave][1] = ss0; sred[wave][2] = s1; sred[wave][3] = ss1; }
    __syncthreads();
    if (tid == 0) {
      float4 p;
      p.x = sred[0][0] + sred[1][0] + sred[2][0] + sred[3][0];
      p.y = sred[0][1] + sred[1][1] + sred[2][1] + sred[3][1];
      p.z = sred[0][2] + sred[1][2] + sred[2][2] + sred[3][2];
      p.w = sred[0][3] + sred[1][3] + sred[2][3] + sred[3][3];
      part[blockIdx.x] = p;
    }
  }
}

// ---------------- host ----------------
extern "C" void kernel_launch(void* const* d_in, const int* in_sizes, int n_in,
                              void* d_out, int out_size, void* d_ws, size_t ws_size,
                              hipStream_t stream) {
  (void)in_sizes; (void)n_in; (void)out_size; (void)ws_size;
  const float* x      = (const float*)d_in[0];
  const float* cond_x = (const float*)d_in[1];
  const float* t      = (const float*)d_in[3];
  const int*   ei     = (const int*)d_in[4];
  const float* w_c0 = (const float*)d_in[5];  const float* b_c0 = (const float*)d_in[6];
  const float* w_l0 = (const float*)d_in[7];  const float* b_l0 = (const float*)d_in[8];
  const float* w_c1 = (const float*)d_in[9];  const float* b_c1 = (const float*)d_in[10];
  const float* w_l1 = (const float*)d_in[11]; const float* b_l1 = (const float*)d_in[12];
  const float* w_c2 = (const float*)d_in[13]; const float* b_c2 = (const float*)d_in[14];
  const float* w_l2 = (const float*)d_in[15]; const float* b_l2 = (const float*)d_in[16];
  const float* gn_g = (const float*)d_in[17]; const float* gn_b = (const float*)d_in[18];
  const float* film_w = (const float*)d_in[19]; const float* film_b = (const float*)d_in[20];

  char* wsp = (char*)d_ws;
  size_t off = 0;
  auto alloc = [&](size_t bytes) -> char* {
    char* p = wsp + off; off += (bytes + 255) & ~(size_t)255; return p;
  };
  constexpr int GM64 = (M_ + 63) / 64;  // 1563
  int*   cnt       = (int*)  alloc((size_t)V_ * 4);
  int*   row_ptr   = (int*)  alloc((size_t)(V_ + 1) * 4);
  int*   cursor    = (int*)  alloc((size_t)V_ * 4);
  int2*  csr       = (int2*) alloc((size_t)E_ * 8);
  int*   scan_tmp  = (int*)  alloc((size_t)V_ * 4);
  int*   scan_bsum = (int*)  alloc(64 * 4);
  float* dinv      = (float*)alloc((size_t)V_ * 4);
  float* rowsum    = (float*)alloc((size_t)V_ * 4);
  float* stats     = (float*)alloc(16);
  float4* part     = (float4*)alloc((size_t)GM64 * 16);
  float* gb        = (float*)alloc(2 * 512 * 4);
  float* kc        = (float*)alloc(2 * HID_ * 4);
  u16* wc0T  = (u16*)alloc((size_t)256 * 160 * 2);
  u16* wl0T  = (u16*)alloc((size_t)256 * 256 * 2);
  u16* wc1Tg = (u16*)alloc((size_t)256 * 256 * 2);
  u16* wl1T  = (u16*)alloc((size_t)256 * 256 * 2);
  u16* wc2T  = (u16*)alloc((size_t)256 * 256 * 2);
  u16* wl2T  = (u16*)alloc((size_t)128 * 256 * 2);
  u16* A0    = (u16*)alloc((size_t)MP_ * K0_ * 2);
  u16* HA0   = (u16*)alloc((size_t)MP_ * K0_ * 2);
  u16* HB    = (u16*)alloc((size_t)MP_ * HID_ * 2);
  u16* HA1   = (u16*)alloc((size_t)MP_ * HID_ * 2);

  const int* srcI = ei;
  const int* dstI = ei + E_;

  hipMemsetAsync(cnt, 0, (size_t)V_ * 4, stream);

  constexpr int NBLK = (V_ + 1023) / 1024;  // 49
  k_count<<<dim3((E_ + 255) / 256), dim3(256), 0, stream>>>(dstI, cnt);
  k_dinv <<<dim3((V_ + 255) / 256), dim3(256), 0, stream>>>(cnt, dinv);
  k_scan1<<<dim3(NBLK), dim3(1024), 0, stream>>>(cnt, scan_tmp, scan_bsum);
  k_scan2<<<dim3(1), dim3(64), 0, stream>>>(scan_bsum, NBLK);
  k_scan3<<<dim3((V_ + 255) / 256), dim3(256), 0, stream>>>(cnt, scan_tmp, scan_bsum, row_ptr, cursor);
  k_fill <<<dim3((E_ + 255) / 256), dim3(256), 0, stream>>>(srcI, dstI, dinv, cursor, csr);
  k_rowsum<<<dim3((V_ + 255) / 256), dim3(256), 0, stream>>>(dinv, row_ptr, csr, rowsum);
  k_film <<<dim3(2), dim3(512), 0, stream>>>(t, film_w, film_b, gb);

  k_wconv  <<<dim3((160 * 256 + 255) / 256), dim3(256), 0, stream>>>(w_c0, wc0T, 160, 256);
  k_wconv  <<<dim3((256 * 256 + 255) / 256), dim3(256), 0, stream>>>(w_l0, wl0T, 256, 256);
  k_wconv_g<<<dim3((256 * 256 + 255) / 256), dim3(256), 0, stream>>>(w_c1, gn_g, wc1Tg, 256, 256);
  k_wconv  <<<dim3((256 * 256 + 255) / 256), dim3(256), 0, stream>>>(w_l1, wl1T, 256, 256);
  k_wconv  <<<dim3((256 * 256 + 255) / 256), dim3(256), 0, stream>>>(w_c2, wc2T, 256, 256);
  k_wconv  <<<dim3((256 * 128 + 255) / 256), dim3(256), 0, stream>>>(w_l2, wl2T, 256, 128);

  k_prep0<<<dim3(M_ * K0_ / 4 / 256), dim3(256), 0, stream>>>(x, cond_x, A0);

  // layer 0: agg(A0) ; fused [GCN0+relu -> Lin0+relu (+GN partials)]
  k_gather<160><<<dim3(V_), 256, 0, stream>>>(A0, dinv, row_ptr, csr, HA0);
  k_pair<0, 1, 160, 256><<<dim3(GM64), 256, 0, stream>>>(
      HA0, wc0T, wl0T, b_c0, b_l0, nullptr, nullptr, nullptr, nullptr, nullptr, part, HB);

  // GroupNorm stats + fold constants
  k_gnreduce<<<dim3(1), dim3(256), 0, stream>>>(part, GM64, stats);
  k_gnfold <<<dim3(256), dim3(256), 0, stream>>>(gn_g, gn_b, w_c1, stats, kc);

  // layer 1: agg(HB) ; fused [GN-folded GCN1+relu -> Lin1+relu]
  k_gather<256><<<dim3(V_), 256, 0, stream>>>(HB, dinv, row_ptr, csr, HA1);
  k_pair<1, 0, 256, 256><<<dim3(GM64), 256, 0, stream>>>(
      HA1, wc1Tg, wl1T, b_c1, b_l1, stats, kc, rowsum, nullptr, nullptr, nullptr, HB);

  // layer 2: agg(HB) ; fused [GCN2+FiLM+relu -> Lin2 + residual -> f32 out]
  k_gather<256><<<dim3(V_), 256, 0, stream>>>(HB, dinv, row_ptr, csr, HA1);
  k_pair<2, 2, 256, 128><<<dim3(GM64), 256, 0, stream>>>(
      HA1, wc2T, wl2T, b_c2, b_l2, nullptr, nullptr, nullptr, gb, x, nullptr, (void*)d_out);
}

// Round 16
// 511.195 us; speedup vs baseline: 1.1364x; 1.1364x over previous
//
#include <hip/hip_runtime.h>
#include <stdint.h>

typedef unsigned short u16;
typedef short bf16x8 __attribute__((ext_vector_type(8)));
typedef float f32x4 __attribute__((ext_vector_type(4)));

constexpr int B_ = 2, V_ = 50000, E_ = 400000;
constexpr int FIN_ = 128, COND_ = 32, HID_ = 256, OUT_ = 128, ENC_ = 64;
constexpr int M_ = B_ * V_;          // 100000
constexpr int MP_ = M_ + 256;        // padded rows for glds staging overrun
constexpr int K0_ = FIN_ + COND_;    // 160
constexpr float EPS_ = 1e-5f;

#define DEV static __device__ __forceinline__

DEV float b2f(u16 u) { union { float f; uint32_t i; } x; x.i = ((uint32_t)u) << 16; return x.f; }
DEV u16 f2b(float f) {
  union { float f; uint32_t i; } x; x.f = f;
  uint32_t r = x.i + 0x7fffu + ((x.i >> 16) & 1u);
  return (u16)(r >> 16);
}
DEV uint32_t pk2(float a, float b) { return (uint32_t)f2b(a) | ((uint32_t)f2b(b) << 16); }

#define GLDS16(gp, lp) __builtin_amdgcn_global_load_lds( \
    (const __attribute__((address_space(1))) void*)(gp), \
    (__attribute__((address_space(3))) void*)(lp), 16, 0, 0)

// ---------------- graph preprocessing ----------------
__global__ void k_count(const int* __restrict__ dst, int* __restrict__ cnt) {
  int e = blockIdx.x * blockDim.x + threadIdx.x;
  if (e < E_) atomicAdd(&cnt[dst[e]], 1);
}

__global__ void k_dinv(const int* __restrict__ cnt, float* __restrict__ dinv) {
  int v = blockIdx.x * blockDim.x + threadIdx.x;
  if (v < V_) dinv[v] = rsqrtf(1.0f + (float)cnt[v]);
}

__global__ __launch_bounds__(1024) void k_scan1(const int* __restrict__ cnt,
                                                int* __restrict__ tmp, int* __restrict__ bsum) {
  __shared__ int s[1024];
  int tid = threadIdx.x;
  int i = blockIdx.x * 1024 + tid;
  int v = (i < V_) ? cnt[i] : 0;
  s[tid] = v;
  __syncthreads();
  for (int off = 1; off < 1024; off <<= 1) {
    int t = (tid >= off) ? s[tid - off] : 0;
    __syncthreads();
    s[tid] += t;
    __syncthreads();
  }
  if (i < V_) tmp[i] = s[tid];
  if (tid == 1023) bsum[blockIdx.x] = s[1023];
}

__global__ void k_scan2(int* __restrict__ bsum, int n) {
  if (threadIdx.x == 0) {
    int a = 0;
    for (int i = 0; i < n; ++i) { a += bsum[i]; bsum[i] = a; }
  }
}

__global__ void k_scan3(const int* __restrict__ cnt, const int* __restrict__ tmp,
                        const int* __restrict__ bsum, int* __restrict__ row_ptr,
                        int* __restrict__ cursor) {
  int i = blockIdx.x * blockDim.x + threadIdx.x;
  if (i >= V_) return;
  int blk = i >> 10;
  int offs = blk ? bsum[blk - 1] : 0;
  int incl = tmp[i] + offs;
  row_ptr[i + 1] = incl;
  cursor[i] = incl - cnt[i];
  if (i == 0) row_ptr[0] = 0;
}

__global__ void k_fill(const int* __restrict__ src, const int* __restrict__ dst,
                       const float* __restrict__ dinv,
                       int* __restrict__ cursor, int2* __restrict__ csr) {
  int e = blockIdx.x * blockDim.x + threadIdx.x;
  if (e < E_) {
    int s = src[e], d = dst[e];
    int p = atomicAdd(&cursor[d], 1);
    float cf = dinv[s] * dinv[d];
    csr[p] = make_int2(s, __float_as_int(cf));
  }
}

// rowsum[v] = dv^2 + sum of edge coefs (for GN affine commute)
__global__ void k_rowsum(const float* __restrict__ dinv, const int* __restrict__ row_ptr,
                         const int2* __restrict__ csr, float* __restrict__ rowsum) {
  int v = blockIdx.x * blockDim.x + threadIdx.x;
  if (v >= V_) return;
  float dv = dinv[v];
  float s = dv * dv;
  int e = row_ptr[v + 1];
  for (int j = row_ptr[v]; j < e; ++j) s += __int_as_float(csr[j].y);
  rowsum[v] = s;
}

// ---------------- small dense helpers ----------------
__global__ void k_film(const float* __restrict__ t, const float* __restrict__ fw,
                       const float* __restrict__ fb, float* __restrict__ gb) {
  int b = blockIdx.x; int j = threadIdx.x;   // blockDim = 512
  float acc = fb[j];
  for (int k = 0; k < ENC_; ++k) acc += t[b * ENC_ + k] * fw[k * 512 + j];
  gb[b * 512 + j] = acc;
}

// merged transpose of the 5 plain (non-gamma) weights in one launch
struct WcDesc { const float* W; u16* WT; int K, N, base; };
__global__ void k_wconv5(WcDesc d0, WcDesc d1, WcDesc d2, WcDesc d3, WcDesc d4, int total) {
  int idx = blockIdx.x * blockDim.x + threadIdx.x;
  if (idx >= total) return;
  WcDesc d;
  if      (idx >= d4.base) d = d4;
  else if (idx >= d3.base) d = d3;
  else if (idx >= d2.base) d = d2;
  else if (idx >= d1.base) d = d1;
  else                     d = d0;
  int i = idx - d.base;
  int k = i / d.N, n = i % d.N;
  d.WT[n * d.K + k] = f2b(d.W[i]);
}

// gamma-scaled weight transpose (GroupNorm fold)
__global__ void k_wconv_g(const float* __restrict__ W, const float* __restrict__ gng,
                          u16* __restrict__ WT, int K, int N) {
  int idx = blockIdx.x * blockDim.x + threadIdx.x;
  if (idx < K * N) {
    int k = idx / N, n = idx % N;
    WT[n * K + k] = f2b(W[idx] * gng[k]);
  }
}

__global__ void k_gnreduce(const float4* __restrict__ part, int nblk,
                           float* __restrict__ stats) {
  int tid = threadIdx.x;  // 256
  float s0 = 0.f, ss0 = 0.f, s1 = 0.f, ss1 = 0.f;
  for (int i = tid; i < nblk; i += 256) {
    float4 p = part[i];
    s0 += p.x; ss0 += p.y; s1 += p.z; ss1 += p.w;
  }
  __shared__ float red[4][4];
#pragma unroll
  for (int o = 32; o > 0; o >>= 1) {
    s0  += __shfl_down(s0, o, 64);
    ss0 += __shfl_down(ss0, o, 64);
    s1  += __shfl_down(s1, o, 64);
    ss1 += __shfl_down(ss1, o, 64);
  }
  int w = tid >> 6, ln = tid & 63;
  if (ln == 0) { red[w][0] = s0; red[w][1] = ss0; red[w][2] = s1; red[w][3] = ss1; }
  __syncthreads();
  if (tid == 0) {
    float S0 = red[0][0] + red[1][0] + red[2][0] + red[3][0];
    float SS0 = red[0][1] + red[1][1] + red[2][1] + red[3][1];
    float S1 = red[0][2] + red[1][2] + red[2][2] + red[3][2];
    float SS1 = red[0][3] + red[1][3] + red[2][3] + red[3][3];
    float n = (float)V_ * (float)HID_;
    float mu0 = S0 / n, var0 = SS0 / n - mu0 * mu0;
    float mu1 = S1 / n, var1 = SS1 / n - mu1 * mu1;
    stats[0] = mu0; stats[1] = rsqrtf(var0 + EPS_);
    stats[2] = mu1; stats[3] = rsqrtf(var1 + EPS_);
  }
}

__global__ void k_gnfold(const float* __restrict__ gng, const float* __restrict__ gnb,
                         const float* __restrict__ W, const float* __restrict__ stats,
                         float* __restrict__ kc) {
  int n = blockIdx.x, c = threadIdx.x;
  float wv = W[c * HID_ + n];
  float gw = gng[c] * wv, bw = gnb[c] * wv;
  __shared__ float sg[4], sb[4];
#pragma unroll
  for (int o = 32; o > 0; o >>= 1) {
    gw += __shfl_down(gw, o, 64);
    bw += __shfl_down(bw, o, 64);
  }
  int w = c >> 6, ln = c & 63;
  if (ln == 0) { sg[w] = gw; sb[w] = bw; }
  __syncthreads();
  if (c == 0) {
    float G = sg[0] + sg[1] + sg[2] + sg[3];
    float Bw = sb[0] + sb[1] + sb[2] + sb[3];
    for (int b = 0; b < B_; ++b)
      kc[b * HID_ + n] = Bw - stats[b * 2] * stats[b * 2 + 1] * G;
  }
}

__global__ void k_prep0(const float* __restrict__ x, const float* __restrict__ cond,
                        u16* __restrict__ A0) {
  int idx = blockIdx.x * blockDim.x + threadIdx.x;
  if (idx >= M_ * K0_ / 4) return;
  int e = idx * 4;
  int r = e / K0_, c = e % K0_;
  float4 v;
  if (c < FIN_) v = *(const float4*)&x[(size_t)r * FIN_ + c];
  else { int vv = r % V_; v = *(const float4*)&cond[(size_t)vv * COND_ + (c - FIN_)]; }
  uint2 o;
  o.x = pk2(v.x, v.y);
  o.y = pk2(v.z, v.w);
  *(uint2*)&A0[e] = o;
}

// ---------------- GCN gather: PURE aggregation (R10-proven) ----------------
template<int KW>
__global__ __launch_bounds__(256) void k_gather(
    const u16* __restrict__ hw, const float* __restrict__ dinv,
    const int* __restrict__ row_ptr, const int2* __restrict__ csr,
    u16* __restrict__ out)
{
  __shared__ f32x4 redA[3][2][32];
  __shared__ f32x4 redB[3][2][32];
  const int v   = blockIdx.x;
  const int tid = threadIdx.x;
  const int nb  = tid >> 6;
  const int b   = (tid >> 5) & 1;
  const int l   = tid & 31;
  const int c0  = l * 8;
  const bool act = l < (KW / 8);

  const float dv = dinv[v];
  const int beg = row_ptr[v], end = row_ptr[v + 1];

  float acc[8];
#pragma unroll
  for (int k = 0; k < 8; ++k) acc[k] = 0.f;

  if (act) {
    int j = beg + nb;
    for (; j + 4 < end; j += 8) {
      int2 e0 = csr[j];
      int2 e1 = csr[j + 4];
      float cf0 = __int_as_float(e0.y);
      float cf1 = __int_as_float(e1.y);
      uint4 u0 = *(const uint4*)&hw[((size_t)b * V_ + e0.x) * KW + c0];
      uint4 u1 = *(const uint4*)&hw[((size_t)b * V_ + e1.x) * KW + c0];
      u16 a0[8]; *(uint4*)a0 = u0;
      u16 a1[8]; *(uint4*)a1 = u1;
#pragma unroll
      for (int k = 0; k < 8; ++k) acc[k] += b2f(a0[k]) * cf0;
#pragma unroll
      for (int k = 0; k < 8; ++k) acc[k] += b2f(a1[k]) * cf1;
    }
    if (j < end) {
      int2 e0 = csr[j];
      float cf0 = __int_as_float(e0.y);
      uint4 u0 = *(const uint4*)&hw[((size_t)b * V_ + e0.x) * KW + c0];
      u16 a0[8]; *(uint4*)a0 = u0;
#pragma unroll
      for (int k = 0; k < 8; ++k) acc[k] += b2f(a0[k]) * cf0;
    }
  }

  if (nb > 0) {
    redA[nb - 1][b][l] = f32x4{acc[0], acc[1], acc[2], acc[3]};
    redB[nb - 1][b][l] = f32x4{acc[4], acc[5], acc[6], acc[7]};
  }
  __syncthreads();
  if (nb == 0 && act) {
#pragma unroll
    for (int g = 0; g < 3; ++g) {
      f32x4 ra = redA[g][b][l], rb = redB[g][b][l];
      acc[0] += ra[0]; acc[1] += ra[1]; acc[2] += ra[2]; acc[3] += ra[3];
      acc[4] += rb[0]; acc[5] += rb[1]; acc[6] += rb[2]; acc[7] += rb[3];
    }
    float sl = dv * dv;
    uint4 u = *(const uint4*)&hw[((size_t)b * V_ + v) * KW + c0];
    u16 us[8]; *(uint4*)us = u;
#pragma unroll
    for (int k = 0; k < 8; ++k) acc[k] += b2f(us[k]) * sl;
    uint4 o;
    o.x = pk2(acc[0], acc[1]);
    o.y = pk2(acc[2], acc[3]);
    o.z = pk2(acc[4], acc[5]);
    o.w = pk2(acc[6], acc[7]);
    *(uint4*)&out[((size_t)b * V_ + v) * KW + c0] = o;
  }
}

// ---------------- fused dual-GEMM (R10-proven) ----------------
// P1E: 0=bias+relu, 1=GN-fold (rs*v + rowsum*kc + bias, relu), 2=bias+FiLM+relu
// P2E: 0=bias+relu->bf16, 1=bias+relu->bf16 + GN stats partials, 2=bias+xres->f32
template<int P1E, int P2E, int K1, int N2>
__global__ __launch_bounds__(256) void k_pair(
    const u16* __restrict__ A, const u16* __restrict__ W1T, const u16* __restrict__ W2T,
    const float* __restrict__ b1, const float* __restrict__ b2,
    const float* __restrict__ stats, const float* __restrict__ kc,
    const float* __restrict__ rowsum, const float* __restrict__ gb,
    const float* __restrict__ xres, float4* __restrict__ part,
    void* __restrict__ Out)
{
  constexpr int BM = 64, BK = 32, N1 = 256;
  constexpr int FN2 = N2 / 64;
  __shared__ alignas(16) u16 Asg[BM * BK];
  __shared__ alignas(16) u16 Bsg[N1 * BK];
  __shared__ alignas(16) u16 T1[BM * N1];
  __shared__ float sred[4][4];
  const int tile_m = blockIdx.x * BM;
  const int tid = threadIdx.x;
  const int wave = tid >> 6, lane = tid & 63;
  const int lr = lane & 15, lkg = lane >> 4;
  const int phys = lkg ^ ((lr >> 1) & 3);

  // ---------------- phase 1 ----------------
  f32x4 acc[4][4];
#pragma unroll
  for (int i = 0; i < 4; ++i)
#pragma unroll
    for (int j = 0; j < 4; ++j) acc[i][j] = {0.f, 0.f, 0.f, 0.f};

  for (int kb = 0; kb < K1; kb += BK) {
    {
      int row = tid >> 2;
      int sslot = (tid & 3) ^ ((row >> 1) & 3);
      GLDS16(A + (size_t)(tile_m + row) * K1 + kb + sslot * 8, &Asg[(wave * 64) * 8]);
    }
#pragma unroll
    for (int it = 0; it < 4; ++it) {
      int c = tid + it * 256;
      int row = c >> 2;
      int sslot = (c & 3) ^ ((row >> 1) & 3);
      GLDS16(W1T + (size_t)row * K1 + kb + sslot * 8, &Bsg[(it * 256 + wave * 64) * 8]);
    }
    __syncthreads();
    bf16x8 af[4], bf[4];
#pragma unroll
    for (int fm = 0; fm < 4; ++fm) af[fm] = *(const bf16x8*)&Asg[(fm * 16 + lr) * BK + phys * 8];
#pragma unroll
    for (int fn = 0; fn < 4; ++fn) bf[fn] = *(const bf16x8*)&Bsg[(wave * 64 + fn * 16 + lr) * BK + phys * 8];
#pragma unroll
    for (int fm = 0; fm < 4; ++fm)
#pragma unroll
      for (int fn = 0; fn < 4; ++fn)
        acc[fm][fn] = __builtin_amdgcn_mfma_f32_16x16x32_bf16(bf[fn], af[fm], acc[fm][fn], 0, 0, 0);
    __syncthreads();
  }

  // epilogue 1 -> T1 (granule-XOR swizzle)
#pragma unroll
  for (int fm = 0; fm < 4; ++fm) {
    const int row = fm * 16 + lr;
    const int gr = tile_m + row;
    const int bb = (gr >= V_) ? 1 : 0;
    float rsc = 1.f, rsum = 0.f;
    if (P1E == 1) {
      rsc = stats[bb * 2 + 1];
      int node = (gr < M_) ? (gr - bb * V_) : 0;
      rsum = rowsum[node];
    }
#pragma unroll
    for (int fn = 0; fn < 4; ++fn) {
      const int colb = wave * 64 + fn * 16 + lkg * 4;
      float v0 = acc[fm][fn][0], v1 = acc[fm][fn][1];
      float v2 = acc[fm][fn][2], v3 = acc[fm][fn][3];
      float4 bs = *(const float4*)&b1[colb];
      if (P1E == 0) {
        v0 = fmaxf(v0 + bs.x, 0.f); v1 = fmaxf(v1 + bs.y, 0.f);
        v2 = fmaxf(v2 + bs.z, 0.f); v3 = fmaxf(v3 + bs.w, 0.f);
      }
      if (P1E == 1) {
        float4 kcv = *(const float4*)&kc[bb * 256 + colb];
        v0 = fmaxf(v0 * rsc + rsum * kcv.x + bs.x, 0.f);
        v1 = fmaxf(v1 * rsc + rsum * kcv.y + bs.y, 0.f);
        v2 = fmaxf(v2 * rsc + rsum * kcv.z + bs.z, 0.f);
        v3 = fmaxf(v3 * rsc + rsum * kcv.w + bs.w, 0.f);
      }
      if (P1E == 2) {
        float4 g = *(const float4*)&gb[bb * 512 + colb];
        float4 be = *(const float4*)&gb[bb * 512 + 256 + colb];
        v0 = fmaxf((v0 + bs.x) * g.x + be.x, 0.f);
        v1 = fmaxf((v1 + bs.y) * g.y + be.y, 0.f);
        v2 = fmaxf((v2 + bs.z) * g.z + be.z, 0.f);
        v3 = fmaxf((v3 + bs.w) * g.w + be.w, 0.f);
      }
      int pg = (colb >> 2) ^ ((row & 7) << 1);
      uint2 o; o.x = pk2(v0, v1); o.y = pk2(v2, v3);
      *(uint2*)&T1[row * 256 + pg * 4] = o;
    }
  }
  __syncthreads();

  // ---------------- phase 2 ----------------
  f32x4 acc2[4][FN2];
#pragma unroll
  for (int i = 0; i < 4; ++i)
#pragma unroll
    for (int j = 0; j < FN2; ++j) acc2[i][j] = {0.f, 0.f, 0.f, 0.f};

  for (int kb2 = 0; kb2 < 256; kb2 += BK) {
#pragma unroll
    for (int it = 0; it < FN2; ++it) {
      int c = tid + it * 256;
      int row = c >> 2;
      int sslot = (c & 3) ^ ((row >> 1) & 3);
      GLDS16(W2T + (size_t)row * 256 + kb2 + sslot * 8, &Bsg[(it * 256 + wave * 64) * 8]);
    }
    __syncthreads();
    bf16x8 af2[4], bf2[FN2];
#pragma unroll
    for (int fm = 0; fm < 4; ++fm) {
      int row = fm * 16 + lr;
      int pg = ((kb2 >> 2) + lkg * 2) ^ ((row & 7) << 1);
      af2[fm] = *(const bf16x8*)&T1[row * 256 + pg * 4];
    }
#pragma unroll
    for (int fn = 0; fn < FN2; ++fn)
      bf2[fn] = *(const bf16x8*)&Bsg[(wave * (N2 / 4) + fn * 16 + lr) * BK + phys * 8];
#pragma unroll
    for (int fm = 0; fm < 4; ++fm)
#pragma unroll
      for (int fn = 0; fn < FN2; ++fn)
        acc2[fm][fn] = __builtin_amdgcn_mfma_f32_16x16x32_bf16(bf2[fn], af2[fm], acc2[fm][fn], 0, 0, 0);
    __syncthreads();
  }

  // epilogue 2 -> global
  float s0 = 0.f, ss0 = 0.f, s1 = 0.f, ss1 = 0.f;
#pragma unroll
  for (int fm = 0; fm < 4; ++fm) {
    const int row = tile_m + fm * 16 + lr;
    if (row >= M_) continue;
#pragma unroll
    for (int fn = 0; fn < FN2; ++fn) {
      const int colb = wave * (N2 / 4) + fn * 16 + lkg * 4;
      float v0 = acc2[fm][fn][0], v1 = acc2[fm][fn][1];
      float v2 = acc2[fm][fn][2], v3 = acc2[fm][fn][3];
      float4 bs = *(const float4*)&b2[colb];
      if (P2E == 0 || P2E == 1) {
        v0 = fmaxf(v0 + bs.x, 0.f); v1 = fmaxf(v1 + bs.y, 0.f);
        v2 = fmaxf(v2 + bs.z, 0.f); v3 = fmaxf(v3 + bs.w, 0.f);
        if (P2E == 1) {
          if (row >= V_) { s1 += v0 + v1 + v2 + v3; ss1 += v0*v0 + v1*v1 + v2*v2 + v3*v3; }
          else           { s0 += v0 + v1 + v2 + v3; ss0 += v0*v0 + v1*v1 + v2*v2 + v3*v3; }
        }
        uint2 o; o.x = pk2(v0, v1); o.y = pk2(v2, v3);
        *(uint2*)&((u16*)Out)[(size_t)row * N2 + colb] = o;
      } else {
        float4 xr = *(const float4*)&xres[(size_t)row * N2 + colb];
        float4 o;
        o.x = v0 + bs.x + xr.x; o.y = v1 + bs.y + xr.y;
        o.z = v2 + bs.z + xr.z; o.w = v3 + bs.w + xr.w;
        *(float4*)&((float*)Out)[(size_t)row * N2 + colb] = o;
      }
    }
  }
  if (P2E == 1) {
#pragma unroll
    for (int o = 32; o > 0; o >>= 1) {
      s0  += __shfl_down(s0, o, 64);
      ss0 += __shfl_down(ss0, o, 64);
      s1  += __shfl_down(s1, o, 64);
      ss1 += __shfl_down(ss1, o, 64);
    }
    if (lane == 0) { sred[wave][0] = s0; sred[wave][1] = ss0; sred[wave][2] = s1; sred[wave][3] = ss1; }
    __syncthreads();
    if (tid == 0) {
      float4 p;
      p.x = sred[0][0] + sred[1][0] + sred[2][0] + sred[3][0];
      p.y = sred[0][1] + sred[1][1] + sred[2][1] + sred[3][1];
      p.z = sred[0][2] + sred[1][2] + sred[2][2] + sred[3][2];
      p.w = sred[0][3] + sred[1][3] + sred[2][3] + sred[3][3];
      part[blockIdx.x] = p;
    }
  }
}

// ---------------- host ----------------
extern "C" void kernel_launch(void* const* d_in, const int* in_sizes, int n_in,
                              void* d_out, int out_size, void* d_ws, size_t ws_size,
                              hipStream_t stream) {
  (void)in_sizes; (void)n_in; (void)out_size; (void)ws_size;
  const float* x      = (const float*)d_in[0];
  const float* cond_x = (const float*)d_in[1];
  const float* t      = (const float*)d_in[3];
  const int*   ei     = (const int*)d_in[4];
  const float* w_c0 = (const float*)d_in[5];  const float* b_c0 = (const float*)d_in[6];
  const float* w_l0 = (const float*)d_in[7];  const float* b_l0 = (const float*)d_in[8];
  const float* w_c1 = (const float*)d_in[9];  const float* b_c1 = (const float*)d_in[10];
  const float* w_l1 = (const float*)d_in[11]; const float* b_l1 = (const float*)d_in[12];
  const float* w_c2 = (const float*)d_in[13]; const float* b_c2 = (const float*)d_in[14];
  const float* w_l2 = (const float*)d_in[15]; const float* b_l2 = (const float*)d_in[16];
  const float* gn_g = (const float*)d_in[17]; const float* gn_b = (const float*)d_in[18];
  const float* film_w = (const float*)d_in[19]; const float* film_b = (const float*)d_in[20];

  char* wsp = (char*)d_ws;
  size_t off = 0;
  auto alloc = [&](size_t bytes) -> char* {
    char* p = wsp + off; off += (bytes + 255) & ~(size_t)255; return p;
  };
  constexpr int GM64 = (M_ + 63) / 64;  // 1563
  int*   cnt       = (int*)  alloc((size_t)V_ * 4);
  int*   row_ptr   = (int*)  alloc((size_t)(V_ + 1) * 4);
  int*   cursor    = (int*)  alloc((size_t)V_ * 4);
  int2*  csr       = (int2*) alloc((size_t)E_ * 8);
  int*   scan_tmp  = (int*)  alloc((size_t)V_ * 4);
  int*   scan_bsum = (int*)  alloc(64 * 4);
  float* dinv      = (float*)alloc((size_t)V_ * 4);
  float* rowsum    = (float*)alloc((size_t)V_ * 4);
  float* stats     = (float*)alloc(16);
  float4* part     = (float4*)alloc((size_t)GM64 * 16);
  float* gb        = (float*)alloc(2 * 512 * 4);
  float* kc        = (float*)alloc(2 * HID_ * 4);
  u16* wc0T  = (u16*)alloc((size_t)256 * 160 * 2);
  u16* wl0T  = (u16*)alloc((size_t)256 * 256 * 2);
  u16* wc1Tg = (u16*)alloc((size_t)256 * 256 * 2);
  u16* wl1T  = (u16*)alloc((size_t)256 * 256 * 2);
  u16* wc2T  = (u16*)alloc((size_t)256 * 256 * 2);
  u16* wl2T  = (u16*)alloc((size_t)128 * 256 * 2);
  u16* A0    = (u16*)alloc((size_t)MP_ * K0_ * 2);
  u16* HA0   = (u16*)alloc((size_t)MP_ * K0_ * 2);
  u16* HB    = (u16*)alloc((size_t)MP_ * HID_ * 2);
  u16* HA1   = (u16*)alloc((size_t)MP_ * HID_ * 2);

  const int* srcI = ei;
  const int* dstI = ei + E_;

  hipMemsetAsync(cnt, 0, (size_t)V_ * 4, stream);

  constexpr int NBLK = (V_ + 1023) / 1024;  // 49
  k_count<<<dim3((E_ + 255) / 256), dim3(256), 0, stream>>>(dstI, cnt);
  k_dinv <<<dim3((V_ + 255) / 256), dim3(256), 0, stream>>>(cnt, dinv);
  k_scan1<<<dim3(NBLK), dim3(1024), 0, stream>>>(cnt, scan_tmp, scan_bsum);
  k_scan2<<<dim3(1), dim3(64), 0, stream>>>(scan_bsum, NBLK);
  k_scan3<<<dim3((V_ + 255) / 256), dim3(256), 0, stream>>>(cnt, scan_tmp, scan_bsum, row_ptr, cursor);
  k_fill <<<dim3((E_ + 255) / 256), dim3(256), 0, stream>>>(srcI, dstI, dinv, cursor, csr);
  k_rowsum<<<dim3((V_ + 255) / 256), dim3(256), 0, stream>>>(dinv, row_ptr, csr, rowsum);
  k_film <<<dim3(2), dim3(512), 0, stream>>>(t, film_w, film_b, gb);

  // merged: 5 plain weight transposes in one launch
  {
    WcDesc d0{w_c0, wc0T, 160, 256, 0};
    WcDesc d1{w_l0, wl0T, 256, 256, 160 * 256};
    WcDesc d2{w_l1, wl1T, 256, 256, d1.base + 256 * 256};
    WcDesc d3{w_c2, wc2T, 256, 256, d2.base + 256 * 256};
    WcDesc d4{w_l2, wl2T, 256, 128, d3.base + 256 * 256};
    int total = d4.base + 256 * 128;
    // adjust W/WT index bases: kernel uses idx - base into d.W directly
    k_wconv5<<<dim3((total + 255) / 256), dim3(256), 0, stream>>>(d0, d1, d2, d3, d4, total);
  }
  k_wconv_g<<<dim3((256 * 256 + 255) / 256), dim3(256), 0, stream>>>(w_c1, gn_g, wc1Tg, 256, 256);

  k_prep0<<<dim3(M_ * K0_ / 4 / 256), dim3(256), 0, stream>>>(x, cond_x, A0);

  // layer 0: agg(A0) ; fused [GCN0+relu -> Lin0+relu (+GN partials)]
  k_gather<160><<<dim3(V_), 256, 0, stream>>>(A0, dinv, row_ptr, csr, HA0);
  k_pair<0, 1, 160, 256><<<dim3(GM64), 256, 0, stream>>>(
      HA0, wc0T, wl0T, b_c0, b_l0, nullptr, nullptr, nullptr, nullptr, nullptr, part, HB);

  // GroupNorm stats + fold constants
  k_gnreduce<<<dim3(1), dim3(256), 0, stream>>>(part, GM64, stats);
  k_gnfold <<<dim3(256), dim3(256), 0, stream>>>(gn_g, gn_b, w_c1, stats, kc);

  // layer 1: agg(HB) ; fused [GN-folded GCN1+relu -> Lin1+relu]
  k_gather<256><<<dim3(V_), 256, 0, stream>>>(HB, dinv, row_ptr, csr, HA1);
  k_pair<1, 0, 256, 256><<<dim3(GM64), 256, 0, stream>>>(
      HA1, wc1Tg, wl1T, b_c1, b_l1, stats, kc, rowsum, nullptr, nullptr, nullptr, HB);

  // layer 2: agg(HB) ; fused [GCN2+FiLM+relu -> Lin2 + residual -> f32 out]
  k_gather<256><<<dim3(V_), 256, 0, stream>>>(HB, dinv, row_ptr, csr, HA1);
  k_pair<2, 2, 256, 128><<<dim3(GM64), 256, 0, stream>>>(
      HA1, wc2T, wl2T, b_c2, b_l2, nullptr, nullptr, nullptr, gb, x, nullptr, (void*)d_out);
}